// Round 17
// baseline (1946.821 us; speedup 1.0000x reference)
//
#include <hip/hip_runtime.h>
#include <math.h>

#define Bsz 32
#define Hd  512
#define SEQ 128
#define G4H 2048
#define BARSTRIDE 32
#define SLOT 16384   // 32*512 ushorts per h step-slot

typedef __attribute__((ext_vector_type(8))) short bf16x8;
typedef __attribute__((ext_vector_type(4))) float f32x4;
typedef __attribute__((ext_vector_type(4))) unsigned short us4;

__device__ __forceinline__ void gload16(const void* g, void* l) {
  __builtin_amdgcn_global_load_lds(
      (const __attribute__((address_space(1))) unsigned int*)g,
      (__attribute__((address_space(3))) unsigned int*)l, 16, 0, 0);
}

// ---------------- fused bias sums (4 pairs, one launch) ----------------
__global__ __launch_bounds__(256) void bias_all_k(const float* a0, const float* b0, float* o0,
                                                  const float* a1, const float* b1, float* o1,
                                                  const float* a2, const float* b2, float* o2,
                                                  const float* a3, const float* b3, float* o3) {
  int i = blockIdx.x * 256 + threadIdx.x;
  int sel = i >> 11, j = i & 2047;
  const float* a = sel == 0 ? a0 : sel == 1 ? a1 : sel == 2 ? a2 : a3;
  const float* b = sel == 0 ? b0 : sel == 1 ? b1 : sel == 2 ? b2 : b3;
  float* o       = sel == 0 ? o0 : sel == 1 ? o1 : sel == 2 ? o2 : o3;
  o[j] = a[j] + b[j];
}

// ---------------- fused embed + bf16 hi/lo split ----------------
__global__ __launch_bounds__(256) void embed_split_k(const int* __restrict__ idx,
                                                     const float* __restrict__ emb,
                                                     unsigned short* __restrict__ hi,
                                                     unsigned short* __restrict__ lo) {
  int t = blockIdx.x * 256 + threadIdx.x;      // 4096 tokens * 64 f4
  int m = t >> 6, e4 = (t & 63) << 2;
  float4 x = *(const float4*)&emb[(size_t)idx[m] * 256 + e4];
  const float* xp = (const float*)&x;
  us4 h, l;
  #pragma unroll
  for (int e = 0; e < 4; ++e) {
    float v = xp[e];
    unsigned int u = __float_as_uint(v);
    unsigned int hr = (u + 0x7fffu + ((u >> 16) & 1u)) & 0xffff0000u;
    h[e] = (unsigned short)(hr >> 16);
    float rem = v - __uint_as_float(hr);
    unsigned int u2 = __float_as_uint(rem);
    l[e] = (unsigned short)((u2 + 0x7fffu + ((u2 >> 16) & 1u)) >> 16);
  }
  *(us4*)&hi[(size_t)m * 256 + e4] = h;
  *(us4*)&lo[(size_t)m * 256 + e4] = l;
}

// ---------------- fp32 -> bf16 hi/lo split (Wout) ----------------
__global__ __launch_bounds__(256) void split_k(const float* __restrict__ X,
                                               unsigned short* __restrict__ hi,
                                               unsigned short* __restrict__ lo) {
  int i = (blockIdx.x * 256 + threadIdx.x) << 2;
  float4 x = *(const float4*)&X[i];
  const float* xp = (const float*)&x;
  us4 h, l;
  #pragma unroll
  for (int e = 0; e < 4; ++e) {
    float v = xp[e];
    unsigned int u = __float_as_uint(v);
    unsigned int hr = (u + 0x7fffu + ((u >> 16) & 1u)) & 0xffff0000u;
    h[e] = (unsigned short)(hr >> 16);
    float rem = v - __uint_as_float(hr);
    unsigned int u2 = __float_as_uint(rem);
    l[e] = (unsigned short)((u2 + 0x7fffu + ((u2 >> 16) & 1u)) >> 16);
  }
  *(us4*)&hi[i] = h;
  *(us4*)&lo[i] = l;
}

// two 524288-float splits in one launch (enc/dec Wih0)
__global__ __launch_bounds__(256) void wsplit2_k(const float* __restrict__ X0,
                                                 unsigned short* __restrict__ h0, unsigned short* __restrict__ l0,
                                                 const float* __restrict__ X1,
                                                 unsigned short* __restrict__ h1, unsigned short* __restrict__ l1) {
  int bi = blockIdx.x;
  const float* X = bi < 512 ? X0 : X1;
  unsigned short* hh = bi < 512 ? h0 : h1;
  unsigned short* ll = bi < 512 ? l0 : l1;
  int i = (((bi & 511) * 256) + threadIdx.x) << 2;
  float4 x = *(const float4*)&X[i];
  const float* xp = (const float*)&x;
  us4 h, l;
  #pragma unroll
  for (int e = 0; e < 4; ++e) {
    float v = xp[e];
    unsigned int u = __float_as_uint(v);
    unsigned int hr = (u + 0x7fffu + ((u >> 16) & 1u)) & 0xffff0000u;
    h[e] = (unsigned short)(hr >> 16);
    float rem = v - __uint_as_float(hr);
    unsigned int u2 = __float_as_uint(rem);
    l[e] = (unsigned short)((u2 + 0x7fffu + ((u2 >> 16) & 1u)) >> 16);
  }
  *(us4*)&hh[i] = h;
  *(us4*)&ll[i] = l;
}

// ---------------- fused weight pack (6 matrices, one launch) ----------------
__global__ __launch_bounds__(256) void pack_all_k(const float* w0, unsigned short* o0,
                                                  const float* w1, unsigned short* o1,
                                                  const float* w2, unsigned short* o2,
                                                  const float* w3, unsigned short* o3,
                                                  const float* w4, unsigned short* o4,
                                                  const float* w5, unsigned short* o5) {
  __shared__ float Wl[16][512];
  const int sel = blockIdx.x >> 7, blk = blockIdx.x & 127, tid = threadIdx.x;
  const float* W = sel == 0 ? w0 : sel == 1 ? w1 : sel == 2 ? w2 : sel == 3 ? w3 : sel == 4 ? w4 : w5;
  unsigned short* out = sel == 0 ? o0 : sel == 1 ? o1 : sel == 2 ? o2 : sel == 3 ? o3 : sel == 4 ? o4 : o5;
  #pragma unroll
  for (int r = 0; r < 16; ++r) {
    int j = (r >> 2) * 512 + blk * 4 + (r & 3);
    Wl[r][tid]       = W[(size_t)j * 512 + tid];
    Wl[r][tid + 256] = W[(size_t)j * 512 + tid + 256];
  }
  __syncthreads();
  for (int idx = tid; idx < 8192; idx += 256) {
    int kf = idx >> 9, l = (idx >> 3) & 63, e = idx & 7;
    int col = l & 15;
    int kpos = (kf << 5) + ((l >> 4) << 3) + e;
    float v = Wl[col][kpos];
    unsigned int uu = __float_as_uint(v);
    unsigned int hr = (uu + 0x7fffu + ((uu >> 16) & 1u)) & 0xffff0000u;
    float rem = v - __uint_as_float(hr);
    unsigned int u2 = __float_as_uint(rem);
    out[(size_t)blk * 16384 + idx] = (unsigned short)(hr >> 16);
    out[(size_t)blk * 16384 + 8192 + idx] =
        (unsigned short)((u2 + 0x7fffu + ((u2 >> 16) & 1u)) >> 16);
  }
}

// ---------------- bf16 MFMA 3-term merged GEMM, 256x256 tile, 8 waves ----------------
// C = Ahi.Bhi + Ahi.Blo + Alo.Bhi (+bias); wave (wm,wn) owns 128x64.
__global__ __launch_bounds__(512)
void gemm_bfs2_k(const unsigned short* __restrict__ Ahi,
                 const unsigned short* __restrict__ Alo,
                 const unsigned short* __restrict__ Bhi,
                 const unsigned short* __restrict__ Blo,
                 const float* __restrict__ bias,
                 float* __restrict__ C, int K, int ldc, int amode)
{
  __shared__ unsigned short Ash[8192], Asl[8192];   // [256][32]
  __shared__ unsigned short Bsh[8192], Bsl[8192];
  const int tid = threadIdx.x;
  const int m0 = blockIdx.x << 8, n0 = blockIdx.y << 8;
  const int lane = tid & 63, wave = tid >> 6;
  const int wm = wave >> 2, wn = wave & 3;
  const int srow = wave * 32 + (lane >> 2);
  const int sk = (lane & 3) << 3;
  const int ldse = wave * 1024 + lane * 8;
  const int fr = lane & 15, fk = (lane >> 4) << 3;

  const int r1 = m0 + srow, r2 = m0 + srow + 16;
  const size_t ra1 = amode ? ((size_t)(r1 & 127) * 32 + (r1 >> 7)) * 512 : (size_t)r1 * K;
  const size_t ra2 = amode ? ((size_t)(r2 & 127) * 32 + (r2 >> 7)) * 512 : (size_t)r2 * K;
  const size_t rb1 = (size_t)(n0 + srow) * K, rb2 = (size_t)(n0 + srow + 16) * K;

  f32x4 acc[8][4];
  #pragma unroll
  for (int a = 0; a < 8; ++a)
    #pragma unroll
    for (int b = 0; b < 4; ++b) acc[a][b] = (f32x4){0.f, 0.f, 0.f, 0.f};

  #pragma unroll 1
  for (int kt = 0; kt < K; kt += 32) {
    gload16(Ahi + ra1 + kt + sk, &Ash[ldse]);
    gload16(Ahi + ra2 + kt + sk, &Ash[ldse + 512]);
    gload16(Alo + ra1 + kt + sk, &Asl[ldse]);
    gload16(Alo + ra2 + kt + sk, &Asl[ldse + 512]);
    gload16(Bhi + rb1 + kt + sk, &Bsh[ldse]);
    gload16(Bhi + rb2 + kt + sk, &Bsh[ldse + 512]);
    gload16(Blo + rb1 + kt + sk, &Bsl[ldse]);
    gload16(Blo + rb2 + kt + sk, &Bsl[ldse + 512]);
    __syncthreads();
    bf16x8 bfh[4], bfl[4];
    #pragma unroll
    for (int nf = 0; nf < 4; ++nf) {
      bfh[nf] = *(const bf16x8*)&Bsh[(wn * 64 + nf * 16 + fr) * 32 + fk];
      bfl[nf] = *(const bf16x8*)&Bsl[(wn * 64 + nf * 16 + fr) * 32 + fk];
    }
    #pragma unroll
    for (int mf = 0; mf < 8; ++mf) {
      bf16x8 afh = *(const bf16x8*)&Ash[(wm * 128 + mf * 16 + fr) * 32 + fk];
      bf16x8 afl = *(const bf16x8*)&Asl[(wm * 128 + mf * 16 + fr) * 32 + fk];
      #pragma unroll
      for (int nf = 0; nf < 4; ++nf) {
        acc[mf][nf] = __builtin_amdgcn_mfma_f32_16x16x32_bf16(afh, bfh[nf],
                                                              acc[mf][nf], 0, 0, 0);
        acc[mf][nf] = __builtin_amdgcn_mfma_f32_16x16x32_bf16(afh, bfl[nf],
                                                              acc[mf][nf], 0, 0, 0);
        acc[mf][nf] = __builtin_amdgcn_mfma_f32_16x16x32_bf16(afl, bfh[nf],
                                                              acc[mf][nf], 0, 0, 0);
      }
    }
    __syncthreads();
  }

  const int rgrp = (lane >> 4) << 2;
  #pragma unroll
  for (int nf = 0; nf < 4; ++nf) {
    int n = n0 + wn * 64 + nf * 16 + fr;
    float bn = bias[n];
    #pragma unroll
    for (int mf = 0; mf < 8; ++mf) {
      #pragma unroll
      for (int r = 0; r < 4; ++r) {
        int m = m0 + wm * 128 + mf * 16 + rgrp + r;
        C[(size_t)m * ldc + n] = acc[mf][nf][r] + bn;
      }
    }
  }
}

// ---------------- spread-flag sync (128 flags per domain, 1 cacheline each) ----------------
__device__ __forceinline__ void pollwait(const int* arr, int target) {
  const int tid = threadIdx.x;
  if (tid < 64) {
    const int* p0 = &arr[tid * BARSTRIDE];
    const int* p1 = &arr[(tid + 64) * BARSTRIDE];
    for (;;) {
      int a = __hip_atomic_load(p0, __ATOMIC_RELAXED, __HIP_MEMORY_SCOPE_AGENT);
      int b = __hip_atomic_load(p1, __ATOMIC_RELAXED, __HIP_MEMORY_SCOPE_AGENT);
      if (__all(min(a, b) >= target)) break;
      __builtin_amdgcn_s_sleep(1);
    }
  }
  __syncthreads();
}

// ---------------- persistent LSTM (byte-identical to round 16) ----------------
__global__ __launch_bounds__(256, 1)
void lstm_seq_k(const unsigned short* __restrict__ pw0,
                const unsigned short* __restrict__ pw1a,
                const unsigned short* __restrict__ pw1b,
                const float* __restrict__ x0pre,
                const float* __restrict__ bias1,
                unsigned short* __restrict__ h0hi, unsigned short* __restrict__ h0lo,
                unsigned short* __restrict__ h1hi, unsigned short* __restrict__ h1lo,
                const unsigned short* __restrict__ h0ihi, const unsigned short* __restrict__ h0ilo,
                const unsigned short* __restrict__ h1ihi, const unsigned short* __restrict__ h1ilo,
                const float* __restrict__ c0init, const float* __restrict__ c1init,
                float* __restrict__ c0fin, float* __restrict__ c1fin,
                int* __restrict__ flagbase)
{
  __shared__ unsigned short wlds[49152];
  __shared__ float gpart[3264];           // [12][16][17]
  __shared__ float gx[256];
  __shared__ unsigned short hstage[256];

  const int blk = blockIdx.x, tid = threadIdx.x;
  const int dom = blk & 1, cb = blk >> 1;
  const int bb0 = dom << 4;
  int* flag = flagbase + dom * 4096;
  const int w = tid >> 6, lane = tid & 63;
  const int fr = lane & 15, fgk = (lane >> 4) << 3;

  {
    const uint4* s0 = (const uint4*)(pw0 + (size_t)cb * 16384);
    const uint4* s1 = (const uint4*)(pw1a + (size_t)cb * 16384);
    const uint4* s2 = (const uint4*)(pw1b + (size_t)cb * 16384);
    uint4* d = (uint4*)wlds;
    for (int i = tid; i < 2048; i += 256) {
      d[i] = s0[i]; d[2048 + i] = s1[i]; d[4096 + i] = s2[i];
    }
  }

  const int b2 = tid & 15, cl = (tid >> 4) & 3;
  const int nn = cb * 4 + cl;
  const int gb = bb0 + b2;
  float creg = 0.f, bv0 = 0.f, bv1 = 0.f, bv2 = 0.f, bv3 = 0.f;
  if (tid < 64) {
    creg = c0init[gb * 512 + nn];
  } else if (tid < 128) {
    creg = c1init[gb * 512 + nn];
    bv0 = bias1[nn]; bv1 = bias1[512 + nn];
    bv2 = bias1[1024 + nn]; bv3 = bias1[1536 + nn];
  }
  const int xcol = tid & 15, xb = (tid >> 4) & 15;
  const int xj = (xcol >> 2) * 512 + cb * 4 + (xcol & 3);
  const int xgb = bb0 + xb;
  __syncthreads();

  #pragma unroll 1
  for (int u = 0; u <= SEQ; ++u) {
    const bool doL0 = (u < SEQ), doL1 = (u >= 1);

    float xv = doL0 ? x0pre[((size_t)xgb * SEQ + u) * G4H + xj] : 0.f;

    if (u > 0) pollwait(flag, u);

    if (doL0) gx[xcol * 16 + xb] = xv;

    const unsigned short* hAh = (u == 0) ? h0ihi : h0hi + (size_t)(u - 1) * SLOT;
    const unsigned short* hAl = (u == 0) ? h0ilo : h0lo + (size_t)(u - 1) * SLOT;
    const unsigned short* hBh = (u <= 1) ? h1ihi : h1hi + (size_t)(u - 2) * SLOT;
    const unsigned short* hBl = (u <= 1) ? h1ilo : h1lo + (size_t)(u - 2) * SLOT;

    f32x4 acc[3];
    acc[0] = (f32x4){0.f, 0.f, 0.f, 0.f};
    acc[1] = (f32x4){0.f, 0.f, 0.f, 0.f};
    acc[2] = (f32x4){0.f, 0.f, 0.f, 0.f};

    #pragma unroll
    for (int q = 0; q < 4; ++q) {
      const int kf = (w << 2) + q;
      const int ko = (kf << 5) + fgk;
      const int wko = (kf << 9) + lane * 8;
      const size_t arow = (size_t)(bb0 + fr) * 512 + ko;
      bf16x8 ah = *(const bf16x8*)&hAh[arow];
      bf16x8 al = *(const bf16x8*)&hAl[arow];
      if (doL0) {
        bf16x8 bh = *(const bf16x8*)&wlds[wko];
        bf16x8 bl = *(const bf16x8*)&wlds[8192 + wko];
        acc[0] = __builtin_amdgcn_mfma_f32_16x16x32_bf16(ah, bh, acc[0], 0, 0, 0);
        acc[0] = __builtin_amdgcn_mfma_f32_16x16x32_bf16(ah, bl, acc[0], 0, 0, 0);
        acc[0] = __builtin_amdgcn_mfma_f32_16x16x32_bf16(al, bh, acc[0], 0, 0, 0);
      }
      if (doL1) {
        bf16x8 bh = *(const bf16x8*)&wlds[16384 + wko];
        bf16x8 bl = *(const bf16x8*)&wlds[16384 + 8192 + wko];
        acc[1] = __builtin_amdgcn_mfma_f32_16x16x32_bf16(ah, bh, acc[1], 0, 0, 0);
        acc[1] = __builtin_amdgcn_mfma_f32_16x16x32_bf16(ah, bl, acc[1], 0, 0, 0);
        acc[1] = __builtin_amdgcn_mfma_f32_16x16x32_bf16(al, bh, acc[1], 0, 0, 0);
        bf16x8 ch = *(const bf16x8*)&hBh[arow];
        bf16x8 cl8 = *(const bf16x8*)&hBl[arow];
        bf16x8 dh = *(const bf16x8*)&wlds[32768 + wko];
        bf16x8 dl = *(const bf16x8*)&wlds[32768 + 8192 + wko];
        acc[2] = __builtin_amdgcn_mfma_f32_16x16x32_bf16(ch, dh, acc[2], 0, 0, 0);
        acc[2] = __builtin_amdgcn_mfma_f32_16x16x32_bf16(ch, dl, acc[2], 0, 0, 0);
        acc[2] = __builtin_amdgcn_mfma_f32_16x16x32_bf16(cl8, dh, acc[2], 0, 0, 0);
      }
    }

    #pragma unroll
    for (int m = 0; m < 3; ++m)
      #pragma unroll
      for (int j = 0; j < 4; ++j)
        gpart[(m * 4 + w) * 272 + ((lane >> 4) * 4 + j) * 17 + fr] = acc[m][j];
    __syncthreads();

    if (tid < 64 && doL0) {
      float g[4];
      #pragma unroll
      for (int gt = 0; gt < 4; ++gt) {
        float s = gx[(gt * 4 + cl) * 16 + b2];
        #pragma unroll
        for (int ww = 0; ww < 4; ++ww)
          s += gpart[ww * 272 + b2 * 17 + gt * 4 + cl];
        g[gt] = s;
      }
      float i_ = 1.f / (1.f + expf(-g[0]));
      float f_ = 1.f / (1.f + expf(-g[1]));
      float gg = tanhf(g[2]);
      float o_ = 1.f / (1.f + expf(-g[3]));
      float cn = f_ * creg + i_ * gg;
      float hn = o_ * tanhf(cn);
      creg = cn;
      unsigned int uu = __float_as_uint(hn);
      unsigned int hr = (uu + 0x7fffu + ((uu >> 16) & 1u)) & 0xffff0000u;
      float rem = hn - __uint_as_float(hr);
      unsigned int u2 = __float_as_uint(rem);
      hstage[(0 * 16 + b2) * 4 + cl] = (unsigned short)(hr >> 16);
      hstage[(1 * 16 + b2) * 4 + cl] =
          (unsigned short)((u2 + 0x7fffu + ((u2 >> 16) & 1u)) >> 16);
    } else if (tid >= 64 && tid < 128 && doL1) {
      float g[4];
      #pragma unroll
      for (int gt = 0; gt < 4; ++gt) {
        float s = 0.f;
        #pragma unroll
        for (int ww = 0; ww < 4; ++ww)
          s += gpart[(4 + ww) * 272 + b2 * 17 + gt * 4 + cl]
             + gpart[(8 + ww) * 272 + b2 * 17 + gt * 4 + cl];
        g[gt] = s;
      }
      g[0] += bv0; g[1] += bv1; g[2] += bv2; g[3] += bv3;
      float i_ = 1.f / (1.f + expf(-g[0]));
      float f_ = 1.f / (1.f + expf(-g[1]));
      float gg = tanhf(g[2]);
      float o_ = 1.f / (1.f + expf(-g[3]));
      float cn = f_ * creg + i_ * gg;
      float hn = o_ * tanhf(cn);
      creg = cn;
      unsigned int uu = __float_as_uint(hn);
      unsigned int hr = (uu + 0x7fffu + ((uu >> 16) & 1u)) & 0xffff0000u;
      float rem = hn - __uint_as_float(hr);
      unsigned int u2 = __float_as_uint(rem);
      hstage[(2 * 16 + b2) * 4 + cl] = (unsigned short)(hr >> 16);
      hstage[(3 * 16 + b2) * 4 + cl] =
          (unsigned short)((u2 + 0x7fffu + ((u2 >> 16) & 1u)) >> 16);
    }
    __syncthreads();

    if (tid < 64) {
      int layer = (tid >> 5) & 1, hl = (tid >> 4) & 1, bb = tid & 15;
      bool go = layer ? doL1 : doL0;
      if (go) {
        unsigned long long v =
            *(const unsigned long long*)&hstage[((layer * 2 + hl) * 16 + bb) * 4];
        unsigned short* arr = layer ? (hl ? h1lo : h1hi) : (hl ? h0lo : h0hi);
        int slot = layer ? (u - 1) : u;
        __hip_atomic_store(
            (unsigned long long*)&arr[(size_t)slot * SLOT + (bb0 + bb) * 512 + cb * 4],
            v, __ATOMIC_RELAXED, __HIP_MEMORY_SCOPE_AGENT);
      }
    }
    asm volatile("s_waitcnt vmcnt(0)" ::: "memory");
    __syncthreads();
    if (tid == 0)
      __hip_atomic_store(&flag[cb * BARSTRIDE], u + 1,
                         __ATOMIC_RELAXED, __HIP_MEMORY_SCOPE_AGENT);
  }

  if (tid < 64)        c0fin[gb * 512 + nn] = creg;
  else if (tid < 128)  c1fin[gb * 512 + nn] = creg;
}

// ---------------- host ----------------
extern "C" void kernel_launch(void* const* d_in, const int* in_sizes, int n_in,
                              void* d_out, int out_size, void* d_ws, size_t ws_size,
                              hipStream_t stream) {
  const int*   src  = (const int*)d_in[0];
  const int*   tgt  = (const int*)d_in[1];
  const float* emb  = (const float*)d_in[2];
  const float* Wout = (const float*)d_in[3];
  const float* bout = (const float*)d_in[4];
  const float* eWih0 = (const float*)d_in[5];
  const float* eWhh0 = (const float*)d_in[6];
  const float* ebih0 = (const float*)d_in[7];
  const float* ebhh0 = (const float*)d_in[8];
  const float* eWih1 = (const float*)d_in[9];
  const float* eWhh1 = (const float*)d_in[10];
  const float* ebih1 = (const float*)d_in[11];
  const float* ebhh1 = (const float*)d_in[12];
  const float* dWih0 = (const float*)d_in[13];
  const float* dWhh0 = (const float*)d_in[14];
  const float* dbih0 = (const float*)d_in[15];
  const float* dbhh0 = (const float*)d_in[16];
  const float* dWih1 = (const float*)d_in[17];
  const float* dWhh1 = (const float*)d_in[18];
  const float* dbih1 = (const float*)d_in[19];
  const float* dbhh1 = (const float*)d_in[20];

  if (ws_size < 86376448ull) return;

  float* ws = (float*)d_ws;
  char*  wsb = (char*)d_ws;
  unsigned short* PK   = (unsigned short*)(wsb + 37748736);
  unsigned short* PW0E = PK;
  unsigned short* PW1AE = PK + 2097152;
  unsigned short* PW1BE = PK + 4194304;
  unsigned short* PW0D = PK + 6291456;
  unsigned short* PW1AD = PK + 8388608;
  unsigned short* PW1BD = PK + 10485760;
  const size_t OFF_X0   = 1048576;      // fp32 X0 (4M..36M bytes)
  const size_t OFF_BS0E = 15728640;
  const size_t OFF_B1E  = 15730688;
  const size_t OFF_BS0D = 15732736;
  const size_t OFF_B1D  = 15734784;
  const size_t OFF_Z    = 15736832;     // zeros 64KB
  unsigned short* Ehi  = (unsigned short*)(wsb + 63176704);
  unsigned short* Elo  = (unsigned short*)(wsb + 65273856);
  unsigned short* WIhiE = (unsigned short*)(wsb + 67371008);
  unsigned short* WIloE = (unsigned short*)(wsb + 68419584);
  unsigned short* WIhiD = (unsigned short*)(wsb + 0);        // dead EMB region (pre-proj)
  unsigned short* WIloD = (unsigned short*)(wsb + 1048576);
  unsigned short* H0hi = (unsigned short*)(wsb + 69468160);
  unsigned short* H0lo = (unsigned short*)(wsb + 73662464);
  unsigned short* H1hi = (unsigned short*)(wsb + 77856768);
  unsigned short* H1lo = (unsigned short*)(wsb + 82051072);
  unsigned short* Bhi  = (unsigned short*)(wsb + 0);         // overlays (post-dec)
  unsigned short* Blo  = (unsigned short*)(wsb + 32768000);
  float* C0f = (float*)(wsb + 86245376);
  float* C1f = (float*)(wsb + 86310912);
  const unsigned short* ZU = (const unsigned short*)(ws + OFF_Z);
  const float* ZF = ws + OFF_Z;

  int* fb = (int*)(wsb + 63012864);   // 2 dir x 2 dom x 4096 ints
  int* eF = fb;
  int* dF = fb + 8192;

  pack_all_k<<<768, 256, 0, stream>>>(eWhh0, PW0E, eWih1, PW1AE, eWhh1, PW1BE,
                                      dWhh0, PW0D, dWih1, PW1AD, dWhh1, PW1BD);
  bias_all_k<<<32, 256, 0, stream>>>(ebih0, ebhh0, ws + OFF_BS0E,
                                     ebih1, ebhh1, ws + OFF_B1E,
                                     dbih0, dbhh0, ws + OFF_BS0D,
                                     dbih1, dbhh1, ws + OFF_B1D);
  wsplit2_k<<<1024, 256, 0, stream>>>(eWih0, WIhiE, WIloE, dWih0, WIhiD, WIloD);

  // zeros (64KB) + all flag arrays (64KB), contiguous
  hipMemsetAsync(ws + OFF_Z, 0, 131072, stream);

  // ---- encoder ----
  embed_split_k<<<1024, 256, 0, stream>>>(src, emb, Ehi, Elo);
  gemm_bfs2_k<<<dim3(16, 8), 512, 0, stream>>>(Ehi, Elo, WIhiE, WIloE,
                                               ws + OFF_BS0E, ws + OFF_X0, 256, 2048, 0);
  lstm_seq_k<<<256, 256, 0, stream>>>(PW0E, PW1AE, PW1BE,
                                      ws + OFF_X0, ws + OFF_B1E,
                                      H0hi, H0lo, H1hi, H1lo,
                                      ZU, ZU, ZU, ZU,
                                      ZF, ZF,
                                      C0f, C1f,
                                      eF);

  // ---- decoder (inits = encoder finals, slot 127) ----
  embed_split_k<<<1024, 256, 0, stream>>>(tgt, emb, Ehi, Elo);
  gemm_bfs2_k<<<dim3(16, 8), 512, 0, stream>>>(Ehi, Elo, WIhiD, WIloD,
                                               ws + OFF_BS0D, ws + OFF_X0, 256, 2048, 0);
  lstm_seq_k<<<256, 256, 0, stream>>>(PW0D, PW1AD, PW1BD,
                                      ws + OFF_X0, ws + OFF_B1D,
                                      H0hi, H0lo, H1hi, H1lo,
                                      H0hi + (size_t)127 * SLOT, H0lo + (size_t)127 * SLOT,
                                      H1hi + (size_t)127 * SLOT, H1lo + (size_t)127 * SLOT,
                                      C0f, C1f,
                                      C0f, C1f,
                                      dF);

  // ---- vocab projection: A = dec h1 slots (amode=1 row remap), 256^2 tile ----
  split_k<<<16000, 256, 0, stream>>>(Wout, Bhi, Blo);
  gemm_bfs2_k<<<dim3(16, 125), 512, 0, stream>>>(H1hi, H1lo, Bhi, Blo,
                                                 bout, (float*)d_out, 512, 32000, 1);
}

// Round 18
// 1881.924 us; speedup vs baseline: 1.0345x; 1.0345x over previous
//
#include <hip/hip_runtime.h>
#include <math.h>

#define Bsz 32
#define Hd  512
#define SEQ 128
#define G4H 2048
#define BARSTRIDE 32
#define SLOT 16384   // 32*512 ushorts per h step-slot

typedef __attribute__((ext_vector_type(8))) short bf16x8;
typedef __attribute__((ext_vector_type(4))) float f32x4;
typedef __attribute__((ext_vector_type(4))) unsigned short us4;

__device__ __forceinline__ void gload16(const void* g, void* l) {
  __builtin_amdgcn_global_load_lds(
      (const __attribute__((address_space(1))) unsigned int*)g,
      (__attribute__((address_space(3))) unsigned int*)l, 16, 0, 0);
}

// ---------------- fused bias sums (4 pairs, one launch) ----------------
__global__ __launch_bounds__(256) void bias_all_k(const float* a0, const float* b0, float* o0,
                                                  const float* a1, const float* b1, float* o1,
                                                  const float* a2, const float* b2, float* o2,
                                                  const float* a3, const float* b3, float* o3) {
  int i = blockIdx.x * 256 + threadIdx.x;
  int sel = i >> 11, j = i & 2047;
  const float* a = sel == 0 ? a0 : sel == 1 ? a1 : sel == 2 ? a2 : a3;
  const float* b = sel == 0 ? b0 : sel == 1 ? b1 : sel == 2 ? b2 : b3;
  float* o       = sel == 0 ? o0 : sel == 1 ? o1 : sel == 2 ? o2 : o3;
  o[j] = a[j] + b[j];
}

// ---------------- fused embed + bf16 hi/lo split ----------------
__global__ __launch_bounds__(256) void embed_split_k(const int* __restrict__ idx,
                                                     const float* __restrict__ emb,
                                                     unsigned short* __restrict__ hi,
                                                     unsigned short* __restrict__ lo) {
  int t = blockIdx.x * 256 + threadIdx.x;      // 4096 tokens * 64 f4
  int m = t >> 6, e4 = (t & 63) << 2;
  float4 x = *(const float4*)&emb[(size_t)idx[m] * 256 + e4];
  const float* xp = (const float*)&x;
  us4 h, l;
  #pragma unroll
  for (int e = 0; e < 4; ++e) {
    float v = xp[e];
    unsigned int u = __float_as_uint(v);
    unsigned int hr = (u + 0x7fffu + ((u >> 16) & 1u)) & 0xffff0000u;
    h[e] = (unsigned short)(hr >> 16);
    float rem = v - __uint_as_float(hr);
    unsigned int u2 = __float_as_uint(rem);
    l[e] = (unsigned short)((u2 + 0x7fffu + ((u2 >> 16) & 1u)) >> 16);
  }
  *(us4*)&hi[(size_t)m * 256 + e4] = h;
  *(us4*)&lo[(size_t)m * 256 + e4] = l;
}

// ---------------- fp32 -> bf16 hi/lo split (Wout) ----------------
__global__ __launch_bounds__(256) void split_k(const float* __restrict__ X,
                                               unsigned short* __restrict__ hi,
                                               unsigned short* __restrict__ lo) {
  int i = (blockIdx.x * 256 + threadIdx.x) << 2;
  float4 x = *(const float4*)&X[i];
  const float* xp = (const float*)&x;
  us4 h, l;
  #pragma unroll
  for (int e = 0; e < 4; ++e) {
    float v = xp[e];
    unsigned int u = __float_as_uint(v);
    unsigned int hr = (u + 0x7fffu + ((u >> 16) & 1u)) & 0xffff0000u;
    h[e] = (unsigned short)(hr >> 16);
    float rem = v - __uint_as_float(hr);
    unsigned int u2 = __float_as_uint(rem);
    l[e] = (unsigned short)((u2 + 0x7fffu + ((u2 >> 16) & 1u)) >> 16);
  }
  *(us4*)&hi[i] = h;
  *(us4*)&lo[i] = l;
}

// two 524288-float splits in one launch (enc/dec Wih0)
__global__ __launch_bounds__(256) void wsplit2_k(const float* __restrict__ X0,
                                                 unsigned short* __restrict__ h0, unsigned short* __restrict__ l0,
                                                 const float* __restrict__ X1,
                                                 unsigned short* __restrict__ h1, unsigned short* __restrict__ l1) {
  int bi = blockIdx.x;
  const float* X = bi < 512 ? X0 : X1;
  unsigned short* hh = bi < 512 ? h0 : h1;
  unsigned short* ll = bi < 512 ? l0 : l1;
  int i = (((bi & 511) * 256) + threadIdx.x) << 2;
  float4 x = *(const float4*)&X[i];
  const float* xp = (const float*)&x;
  us4 h, l;
  #pragma unroll
  for (int e = 0; e < 4; ++e) {
    float v = xp[e];
    unsigned int u = __float_as_uint(v);
    unsigned int hr = (u + 0x7fffu + ((u >> 16) & 1u)) & 0xffff0000u;
    h[e] = (unsigned short)(hr >> 16);
    float rem = v - __uint_as_float(hr);
    unsigned int u2 = __float_as_uint(rem);
    l[e] = (unsigned short)((u2 + 0x7fffu + ((u2 >> 16) & 1u)) >> 16);
  }
  *(us4*)&hh[i] = h;
  *(us4*)&ll[i] = l;
}

// ---------------- fused weight pack (6 matrices, one launch) ----------------
__global__ __launch_bounds__(256) void pack_all_k(const float* w0, unsigned short* o0,
                                                  const float* w1, unsigned short* o1,
                                                  const float* w2, unsigned short* o2,
                                                  const float* w3, unsigned short* o3,
                                                  const float* w4, unsigned short* o4,
                                                  const float* w5, unsigned short* o5) {
  __shared__ float Wl[16][512];
  const int sel = blockIdx.x >> 7, blk = blockIdx.x & 127, tid = threadIdx.x;
  const float* W = sel == 0 ? w0 : sel == 1 ? w1 : sel == 2 ? w2 : sel == 3 ? w3 : sel == 4 ? w4 : w5;
  unsigned short* out = sel == 0 ? o0 : sel == 1 ? o1 : sel == 2 ? o2 : sel == 3 ? o3 : sel == 4 ? o4 : o5;
  #pragma unroll
  for (int r = 0; r < 16; ++r) {
    int j = (r >> 2) * 512 + blk * 4 + (r & 3);
    Wl[r][tid]       = W[(size_t)j * 512 + tid];
    Wl[r][tid + 256] = W[(size_t)j * 512 + tid + 256];
  }
  __syncthreads();
  for (int idx = tid; idx < 8192; idx += 256) {
    int kf = idx >> 9, l = (idx >> 3) & 63, e = idx & 7;
    int col = l & 15;
    int kpos = (kf << 5) + ((l >> 4) << 3) + e;
    float v = Wl[col][kpos];
    unsigned int uu = __float_as_uint(v);
    unsigned int hr = (uu + 0x7fffu + ((uu >> 16) & 1u)) & 0xffff0000u;
    float rem = v - __uint_as_float(hr);
    unsigned int u2 = __float_as_uint(rem);
    out[(size_t)blk * 16384 + idx] = (unsigned short)(hr >> 16);
    out[(size_t)blk * 16384 + 8192 + idx] =
        (unsigned short)((u2 + 0x7fffu + ((u2 >> 16) & 1u)) >> 16);
  }
}

// ---------------- bf16 MFMA 3-term merged GEMM, 128x128 tile (proven R14-R16) ----------------
__global__ __launch_bounds__(256)
void gemm_bfs_k(const unsigned short* __restrict__ Ahi,
                const unsigned short* __restrict__ Alo,
                const unsigned short* __restrict__ Bhi,
                const unsigned short* __restrict__ Blo,
                const float* __restrict__ bias,
                float* __restrict__ C, int K, int ldc, int amode)
{
  __shared__ unsigned short Ash[4096], Asl[4096];
  __shared__ unsigned short Bsh[4096], Bsl[4096];
  const int tid = threadIdx.x;
  const int m0 = blockIdx.x << 7, n0 = blockIdx.y << 7;
  const int lane = tid & 63, wave = tid >> 6;
  const int wr = wave >> 1, wc = wave & 1;
  const int srow = wave * 32 + (lane >> 2);
  const int sk = (lane & 3) << 3;
  const int ldse = wave * 1024 + lane * 8;
  const int fr = lane & 15, fk = (lane >> 4) << 3;

  const int r1 = m0 + srow, r2 = m0 + srow + 16;
  const size_t ra1 = amode ? ((size_t)(r1 & 127) * 32 + (r1 >> 7)) * 512 : (size_t)r1 * K;
  const size_t ra2 = amode ? ((size_t)(r2 & 127) * 32 + (r2 >> 7)) * 512 : (size_t)r2 * K;
  const size_t rb1 = (size_t)(n0 + srow) * K, rb2 = (size_t)(n0 + srow + 16) * K;

  f32x4 acc[4][4];
  #pragma unroll
  for (int a = 0; a < 4; ++a)
    #pragma unroll
    for (int b = 0; b < 4; ++b) acc[a][b] = (f32x4){0.f, 0.f, 0.f, 0.f};

  #pragma unroll 1
  for (int kt = 0; kt < K; kt += 32) {
    gload16(Ahi + ra1 + kt + sk, &Ash[ldse]);
    gload16(Ahi + ra2 + kt + sk, &Ash[ldse + 512]);
    gload16(Alo + ra1 + kt + sk, &Asl[ldse]);
    gload16(Alo + ra2 + kt + sk, &Asl[ldse + 512]);
    gload16(Bhi + rb1 + kt + sk, &Bsh[ldse]);
    gload16(Bhi + rb2 + kt + sk, &Bsh[ldse + 512]);
    gload16(Blo + rb1 + kt + sk, &Bsl[ldse]);
    gload16(Blo + rb2 + kt + sk, &Bsl[ldse + 512]);
    __syncthreads();
    bf16x8 afh[4], afl[4], bfh[4], bfl[4];
    #pragma unroll
    for (int mf = 0; mf < 4; ++mf) {
      afh[mf] = *(const bf16x8*)&Ash[(wr * 64 + mf * 16 + fr) * 32 + fk];
      afl[mf] = *(const bf16x8*)&Asl[(wr * 64 + mf * 16 + fr) * 32 + fk];
    }
    #pragma unroll
    for (int nf = 0; nf < 4; ++nf) {
      bfh[nf] = *(const bf16x8*)&Bsh[(wc * 64 + nf * 16 + fr) * 32 + fk];
      bfl[nf] = *(const bf16x8*)&Bsl[(wc * 64 + nf * 16 + fr) * 32 + fk];
    }
    #pragma unroll
    for (int mf = 0; mf < 4; ++mf)
      #pragma unroll
      for (int nf = 0; nf < 4; ++nf) {
        acc[mf][nf] = __builtin_amdgcn_mfma_f32_16x16x32_bf16(afh[mf], bfh[nf],
                                                              acc[mf][nf], 0, 0, 0);
        acc[mf][nf] = __builtin_amdgcn_mfma_f32_16x16x32_bf16(afh[mf], bfl[nf],
                                                              acc[mf][nf], 0, 0, 0);
        acc[mf][nf] = __builtin_amdgcn_mfma_f32_16x16x32_bf16(afl[mf], bfh[nf],
                                                              acc[mf][nf], 0, 0, 0);
      }
    __syncthreads();
  }

  const int rgrp = (lane >> 4) << 2;
  #pragma unroll
  for (int nf = 0; nf < 4; ++nf) {
    int n = n0 + wc * 64 + nf * 16 + fr;
    float bn = bias[n];
    #pragma unroll
    for (int mf = 0; mf < 4; ++mf) {
      #pragma unroll
      for (int r = 0; r < 4; ++r) {
        int m = m0 + wr * 64 + mf * 16 + rgrp + r;
        C[(size_t)m * ldc + n] = acc[mf][nf][r] + bn;
      }
    }
  }
}

// ---------------- spread-flag sync (128 flags per domain, 1 cacheline each) ----------------
__device__ __forceinline__ void pollwait(const int* arr, int target) {
  const int tid = threadIdx.x;
  if (tid < 64) {
    const int* p0 = &arr[tid * BARSTRIDE];
    const int* p1 = &arr[(tid + 64) * BARSTRIDE];
    for (;;) {
      int a = __hip_atomic_load(p0, __ATOMIC_RELAXED, __HIP_MEMORY_SCOPE_AGENT);
      int b = __hip_atomic_load(p1, __ATOMIC_RELAXED, __HIP_MEMORY_SCOPE_AGENT);
      if (__all(min(a, b) >= target)) break;
      __builtin_amdgcn_s_sleep(1);
    }
  }
  __syncthreads();
}

// ---------------- persistent LSTM (byte-identical to rounds 16/17) ----------------
__global__ __launch_bounds__(256, 1)
void lstm_seq_k(const unsigned short* __restrict__ pw0,
                const unsigned short* __restrict__ pw1a,
                const unsigned short* __restrict__ pw1b,
                const float* __restrict__ x0pre,
                const float* __restrict__ bias1,
                unsigned short* __restrict__ h0hi, unsigned short* __restrict__ h0lo,
                unsigned short* __restrict__ h1hi, unsigned short* __restrict__ h1lo,
                const unsigned short* __restrict__ h0ihi, const unsigned short* __restrict__ h0ilo,
                const unsigned short* __restrict__ h1ihi, const unsigned short* __restrict__ h1ilo,
                const float* __restrict__ c0init, const float* __restrict__ c1init,
                float* __restrict__ c0fin, float* __restrict__ c1fin,
                int* __restrict__ flagbase)
{
  __shared__ unsigned short wlds[49152];
  __shared__ float gpart[3264];           // [12][16][17]
  __shared__ float gx[256];
  __shared__ unsigned short hstage[256];

  const int blk = blockIdx.x, tid = threadIdx.x;
  const int dom = blk & 1, cb = blk >> 1;
  const int bb0 = dom << 4;
  int* flag = flagbase + dom * 4096;
  const int w = tid >> 6, lane = tid & 63;
  const int fr = lane & 15, fgk = (lane >> 4) << 3;

  {
    const uint4* s0 = (const uint4*)(pw0 + (size_t)cb * 16384);
    const uint4* s1 = (const uint4*)(pw1a + (size_t)cb * 16384);
    const uint4* s2 = (const uint4*)(pw1b + (size_t)cb * 16384);
    uint4* d = (uint4*)wlds;
    for (int i = tid; i < 2048; i += 256) {
      d[i] = s0[i]; d[2048 + i] = s1[i]; d[4096 + i] = s2[i];
    }
  }

  const int b2 = tid & 15, cl = (tid >> 4) & 3;
  const int nn = cb * 4 + cl;
  const int gb = bb0 + b2;
  float creg = 0.f, bv0 = 0.f, bv1 = 0.f, bv2 = 0.f, bv3 = 0.f;
  if (tid < 64) {
    creg = c0init[gb * 512 + nn];
  } else if (tid < 128) {
    creg = c1init[gb * 512 + nn];
    bv0 = bias1[nn]; bv1 = bias1[512 + nn];
    bv2 = bias1[1024 + nn]; bv3 = bias1[1536 + nn];
  }
  const int xcol = tid & 15, xb = (tid >> 4) & 15;
  const int xj = (xcol >> 2) * 512 + cb * 4 + (xcol & 3);
  const int xgb = bb0 + xb;
  __syncthreads();

  #pragma unroll 1
  for (int u = 0; u <= SEQ; ++u) {
    const bool doL0 = (u < SEQ), doL1 = (u >= 1);

    float xv = doL0 ? x0pre[((size_t)xgb * SEQ + u) * G4H + xj] : 0.f;

    if (u > 0) pollwait(flag, u);

    if (doL0) gx[xcol * 16 + xb] = xv;

    const unsigned short* hAh = (u == 0) ? h0ihi : h0hi + (size_t)(u - 1) * SLOT;
    const unsigned short* hAl = (u == 0) ? h0ilo : h0lo + (size_t)(u - 1) * SLOT;
    const unsigned short* hBh = (u <= 1) ? h1ihi : h1hi + (size_t)(u - 2) * SLOT;
    const unsigned short* hBl = (u <= 1) ? h1ilo : h1lo + (size_t)(u - 2) * SLOT;

    f32x4 acc[3];
    acc[0] = (f32x4){0.f, 0.f, 0.f, 0.f};
    acc[1] = (f32x4){0.f, 0.f, 0.f, 0.f};
    acc[2] = (f32x4){0.f, 0.f, 0.f, 0.f};

    #pragma unroll
    for (int q = 0; q < 4; ++q) {
      const int kf = (w << 2) + q;
      const int ko = (kf << 5) + fgk;
      const int wko = (kf << 9) + lane * 8;
      const size_t arow = (size_t)(bb0 + fr) * 512 + ko;
      bf16x8 ah = *(const bf16x8*)&hAh[arow];
      bf16x8 al = *(const bf16x8*)&hAl[arow];
      if (doL0) {
        bf16x8 bh = *(const bf16x8*)&wlds[wko];
        bf16x8 bl = *(const bf16x8*)&wlds[8192 + wko];
        acc[0] = __builtin_amdgcn_mfma_f32_16x16x32_bf16(ah, bh, acc[0], 0, 0, 0);
        acc[0] = __builtin_amdgcn_mfma_f32_16x16x32_bf16(ah, bl, acc[0], 0, 0, 0);
        acc[0] = __builtin_amdgcn_mfma_f32_16x16x32_bf16(al, bh, acc[0], 0, 0, 0);
      }
      if (doL1) {
        bf16x8 bh = *(const bf16x8*)&wlds[16384 + wko];
        bf16x8 bl = *(const bf16x8*)&wlds[16384 + 8192 + wko];
        acc[1] = __builtin_amdgcn_mfma_f32_16x16x32_bf16(ah, bh, acc[1], 0, 0, 0);
        acc[1] = __builtin_amdgcn_mfma_f32_16x16x32_bf16(ah, bl, acc[1], 0, 0, 0);
        acc[1] = __builtin_amdgcn_mfma_f32_16x16x32_bf16(al, bh, acc[1], 0, 0, 0);
        bf16x8 ch = *(const bf16x8*)&hBh[arow];
        bf16x8 cl8 = *(const bf16x8*)&hBl[arow];
        bf16x8 dh = *(const bf16x8*)&wlds[32768 + wko];
        bf16x8 dl = *(const bf16x8*)&wlds[32768 + 8192 + wko];
        acc[2] = __builtin_amdgcn_mfma_f32_16x16x32_bf16(ch, dh, acc[2], 0, 0, 0);
        acc[2] = __builtin_amdgcn_mfma_f32_16x16x32_bf16(ch, dl, acc[2], 0, 0, 0);
        acc[2] = __builtin_amdgcn_mfma_f32_16x16x32_bf16(cl8, dh, acc[2], 0, 0, 0);
      }
    }

    #pragma unroll
    for (int m = 0; m < 3; ++m)
      #pragma unroll
      for (int j = 0; j < 4; ++j)
        gpart[(m * 4 + w) * 272 + ((lane >> 4) * 4 + j) * 17 + fr] = acc[m][j];
    __syncthreads();

    if (tid < 64 && doL0) {
      float g[4];
      #pragma unroll
      for (int gt = 0; gt < 4; ++gt) {
        float s = gx[(gt * 4 + cl) * 16 + b2];
        #pragma unroll
        for (int ww = 0; ww < 4; ++ww)
          s += gpart[ww * 272 + b2 * 17 + gt * 4 + cl];
        g[gt] = s;
      }
      float i_ = 1.f / (1.f + expf(-g[0]));
      float f_ = 1.f / (1.f + expf(-g[1]));
      float gg = tanhf(g[2]);
      float o_ = 1.f / (1.f + expf(-g[3]));
      float cn = f_ * creg + i_ * gg;
      float hn = o_ * tanhf(cn);
      creg = cn;
      unsigned int uu = __float_as_uint(hn);
      unsigned int hr = (uu + 0x7fffu + ((uu >> 16) & 1u)) & 0xffff0000u;
      float rem = hn - __uint_as_float(hr);
      unsigned int u2 = __float_as_uint(rem);
      hstage[(0 * 16 + b2) * 4 + cl] = (unsigned short)(hr >> 16);
      hstage[(1 * 16 + b2) * 4 + cl] =
          (unsigned short)((u2 + 0x7fffu + ((u2 >> 16) & 1u)) >> 16);
    } else if (tid >= 64 && tid < 128 && doL1) {
      float g[4];
      #pragma unroll
      for (int gt = 0; gt < 4; ++gt) {
        float s = 0.f;
        #pragma unroll
        for (int ww = 0; ww < 4; ++ww)
          s += gpart[(4 + ww) * 272 + b2 * 17 + gt * 4 + cl]
             + gpart[(8 + ww) * 272 + b2 * 17 + gt * 4 + cl];
        g[gt] = s;
      }
      g[0] += bv0; g[1] += bv1; g[2] += bv2; g[3] += bv3;
      float i_ = 1.f / (1.f + expf(-g[0]));
      float f_ = 1.f / (1.f + expf(-g[1]));
      float gg = tanhf(g[2]);
      float o_ = 1.f / (1.f + expf(-g[3]));
      float cn = f_ * creg + i_ * gg;
      float hn = o_ * tanhf(cn);
      creg = cn;
      unsigned int uu = __float_as_uint(hn);
      unsigned int hr = (uu + 0x7fffu + ((uu >> 16) & 1u)) & 0xffff0000u;
      float rem = hn - __uint_as_float(hr);
      unsigned int u2 = __float_as_uint(rem);
      hstage[(2 * 16 + b2) * 4 + cl] = (unsigned short)(hr >> 16);
      hstage[(3 * 16 + b2) * 4 + cl] =
          (unsigned short)((u2 + 0x7fffu + ((u2 >> 16) & 1u)) >> 16);
    }
    __syncthreads();

    if (tid < 64) {
      int layer = (tid >> 5) & 1, hl = (tid >> 4) & 1, bb = tid & 15;
      bool go = layer ? doL1 : doL0;
      if (go) {
        unsigned long long v =
            *(const unsigned long long*)&hstage[((layer * 2 + hl) * 16 + bb) * 4];
        unsigned short* arr = layer ? (hl ? h1lo : h1hi) : (hl ? h0lo : h0hi);
        int slot = layer ? (u - 1) : u;
        __hip_atomic_store(
            (unsigned long long*)&arr[(size_t)slot * SLOT + (bb0 + bb) * 512 + cb * 4],
            v, __ATOMIC_RELAXED, __HIP_MEMORY_SCOPE_AGENT);
      }
    }
    asm volatile("s_waitcnt vmcnt(0)" ::: "memory");
    __syncthreads();
    if (tid == 0)
      __hip_atomic_store(&flag[cb * BARSTRIDE], u + 1,
                         __ATOMIC_RELAXED, __HIP_MEMORY_SCOPE_AGENT);
  }

  if (tid < 64)        c0fin[gb * 512 + nn] = creg;
  else if (tid < 128)  c1fin[gb * 512 + nn] = creg;
}

// ---------------- host ----------------
extern "C" void kernel_launch(void* const* d_in, const int* in_sizes, int n_in,
                              void* d_out, int out_size, void* d_ws, size_t ws_size,
                              hipStream_t stream) {
  const int*   src  = (const int*)d_in[0];
  const int*   tgt  = (const int*)d_in[1];
  const float* emb  = (const float*)d_in[2];
  const float* Wout = (const float*)d_in[3];
  const float* bout = (const float*)d_in[4];
  const float* eWih0 = (const float*)d_in[5];
  const float* eWhh0 = (const float*)d_in[6];
  const float* ebih0 = (const float*)d_in[7];
  const float* ebhh0 = (const float*)d_in[8];
  const float* eWih1 = (const float*)d_in[9];
  const float* eWhh1 = (const float*)d_in[10];
  const float* ebih1 = (const float*)d_in[11];
  const float* ebhh1 = (const float*)d_in[12];
  const float* dWih0 = (const float*)d_in[13];
  const float* dWhh0 = (const float*)d_in[14];
  const float* dbih0 = (const float*)d_in[15];
  const float* dbhh0 = (const float*)d_in[16];
  const float* dWih1 = (const float*)d_in[17];
  const float* dWhh1 = (const float*)d_in[18];
  const float* dbih1 = (const float*)d_in[19];
  const float* dbhh1 = (const float*)d_in[20];

  if (ws_size < 86376448ull) return;

  float* ws = (float*)d_ws;
  char*  wsb = (char*)d_ws;
  unsigned short* PK   = (unsigned short*)(wsb + 37748736);
  unsigned short* PW0E = PK;
  unsigned short* PW1AE = PK + 2097152;
  unsigned short* PW1BE = PK + 4194304;
  unsigned short* PW0D = PK + 6291456;
  unsigned short* PW1AD = PK + 8388608;
  unsigned short* PW1BD = PK + 10485760;
  const size_t OFF_X0   = 1048576;      // fp32 X0 (bytes 4.2M..37.7M)
  const size_t OFF_BS0E = 15728640;
  const size_t OFF_B1E  = 15730688;
  const size_t OFF_BS0D = 15732736;
  const size_t OFF_B1D  = 15734784;
  const size_t OFF_Z    = 15736832;     // zeros 64KB
  unsigned short* Ehi  = (unsigned short*)(wsb + 63176704);
  unsigned short* Elo  = (unsigned short*)(wsb + 65273856);
  unsigned short* WIhiE = (unsigned short*)(wsb + 67371008);
  unsigned short* WIloE = (unsigned short*)(wsb + 68419584);
  unsigned short* WIhiD = (unsigned short*)(wsb + 0);        // dead EMB region (pre-proj)
  unsigned short* WIloD = (unsigned short*)(wsb + 1048576);
  unsigned short* H0hi = (unsigned short*)(wsb + 69468160);
  unsigned short* H0lo = (unsigned short*)(wsb + 73662464);
  unsigned short* H1hi = (unsigned short*)(wsb + 77856768);
  unsigned short* H1lo = (unsigned short*)(wsb + 82051072);
  unsigned short* Bhi  = (unsigned short*)(wsb + 0);         // overlays (post-dec)
  unsigned short* Blo  = (unsigned short*)(wsb + 32768000);
  float* C0f = (float*)(wsb + 86245376);
  float* C1f = (float*)(wsb + 86310912);
  const unsigned short* ZU = (const unsigned short*)(ws + OFF_Z);
  const float* ZF = ws + OFF_Z;

  int* fb = (int*)(wsb + 63012864);   // 2 dir x 2 dom x 4096 ints
  int* eF = fb;
  int* dF = fb + 8192;

  pack_all_k<<<768, 256, 0, stream>>>(eWhh0, PW0E, eWih1, PW1AE, eWhh1, PW1BE,
                                      dWhh0, PW0D, dWih1, PW1AD, dWhh1, PW1BD);
  bias_all_k<<<32, 256, 0, stream>>>(ebih0, ebhh0, ws + OFF_BS0E,
                                     ebih1, ebhh1, ws + OFF_B1E,
                                     dbih0, dbhh0, ws + OFF_BS0D,
                                     dbih1, dbhh1, ws + OFF_B1D);
  wsplit2_k<<<1024, 256, 0, stream>>>(eWih0, WIhiE, WIloE, dWih0, WIhiD, WIloD);

  // zeros (64KB) + all flag arrays (64KB), contiguous
  hipMemsetAsync(ws + OFF_Z, 0, 131072, stream);

  // ---- encoder ----
  embed_split_k<<<1024, 256, 0, stream>>>(src, emb, Ehi, Elo);
  gemm_bfs_k<<<dim3(32, 16), 256, 0, stream>>>(Ehi, Elo, WIhiE, WIloE,
                                               ws + OFF_BS0E, ws + OFF_X0, 256, 2048, 0);
  lstm_seq_k<<<256, 256, 0, stream>>>(PW0E, PW1AE, PW1BE,
                                      ws + OFF_X0, ws + OFF_B1E,
                                      H0hi, H0lo, H1hi, H1lo,
                                      ZU, ZU, ZU, ZU,
                                      ZF, ZF,
                                      C0f, C1f,
                                      eF);

  // ---- decoder (inits = encoder finals, slot 127) ----
  embed_split_k<<<1024, 256, 0, stream>>>(tgt, emb, Ehi, Elo);
  gemm_bfs_k<<<dim3(32, 16), 256, 0, stream>>>(Ehi, Elo, WIhiD, WIloD,
                                               ws + OFF_BS0D, ws + OFF_X0, 256, 2048, 0);
  lstm_seq_k<<<256, 256, 0, stream>>>(PW0D, PW1AD, PW1BD,
                                      ws + OFF_X0, ws + OFF_B1D,
                                      H0hi, H0lo, H1hi, H1lo,
                                      H0hi + (size_t)127 * SLOT, H0lo + (size_t)127 * SLOT,
                                      H1hi + (size_t)127 * SLOT, H1lo + (size_t)127 * SLOT,
                                      C0f, C1f,
                                      C0f, C1f,
                                      dF);

  // ---- vocab projection: A = dec h1 slots (amode=1 row remap), 128^2 tile ----
  split_k<<<16000, 256, 0, stream>>>(Wout, Bhi, Blo);
  gemm_bfs_k<<<dim3(32, 250), 256, 0, stream>>>(H1hi, H1lo, Bhi, Blo,
                                                bout, (float*)d_out, 512, 32000, 1);
}